// Round 3
// baseline (126.719 us; speedup 1.0000x reference)
//
#include <hip/hip_runtime.h>
#include <math.h>

#define T_LEN 16384
#define B_ROWS 256
#define BLK 256
#define EPT 8                       // elements per thread
#define COLS (BLK * EPT)            // 2048 columns per block
#define SEG (T_LEN / COLS)          // 8 segments per row
#define GRID (B_ROWS * SEG)         // 2048 blocks

#define LOG2E 1.44269504088896340f
#define LN2   0.69314718055994531f

typedef float v4f __attribute__((ext_vector_type(4)));

__device__ __forceinline__ v4f nt_load4(const float* p) {
    return __builtin_nontemporal_load((const v4f*)p);
}

// fast sigmoid: 1 v_exp + 1 v_rcp
__device__ __forceinline__ float fast_sig(float x) {
    float e = __builtin_amdgcn_exp2f(fabsf(x) * -LOG2E);
    float r = __builtin_amdgcn_rcpf(1.0f + e);
    return (x >= 0.f) ? r : e * r;
}

__global__ __launch_bounds__(BLK, 8) void loss_fused(
    const float* __restrict__ pon, const float* __restrict__ poff,
    const float* __restrict__ ton, const float* __restrict__ toff,
    float* __restrict__ ws, unsigned int* __restrict__ cnt,
    float* __restrict__ out)
{
    const int blk = blockIdx.x;
    const int row = blk >> 3;            // SEG = 8
    const int s   = blk & 7;
    const int tid = threadIdx.x;
    const int C0  = s * COLS;            // segment start (row-local col)
    const int c0  = C0 + tid * EPT;      // this thread's first col
    const size_t rowbase = (size_t)row * T_LEN;

    __shared__ float on_h[BLK * 3];      // each thread's first 3 onset probs
    __shared__ float off_h[BLK * 3];     // each thread's first 3 offset probs
    __shared__ float part[4][9];
    __shared__ int   is_last;

    // accumulators (arithmetic form, t/u are exactly 0.0 or 1.0)
    float on_sp = 0.f, on_tsp = 0.f, on_pos = 0.f, on_cnt = 0.f, on_psum = 0.f;
    float off_sp = 0.f, off_tsp = 0.f, off_pos = 0.f, off_cnt = 0.f, off_psum = 0.f;
    float cons = 0.f;
    float w0 = 0.f, w1 = 0.f, w2 = 0.f;  // rolling window of last 3 onset probs

    const float* pb  = pon  + rowbase + c0;
    const float* fb  = poff + rowbase + c0;
    const float* tb  = ton  + rowbase + c0;
    const float* ub  = toff + rowbase + c0;

    #pragma unroll
    for (int k = 0; k < EPT / 4; k++) {
        v4f xo = nt_load4(pb + 4 * k);
        v4f xf = nt_load4(fb + 4 * k);
        v4f to = nt_load4(tb + 4 * k);
        v4f tf = nt_load4(ub + 4 * k);
        #pragma unroll
        for (int j = 0; j < 4; j++) {
            const int i = 4 * k + j;      // compile-time
            // ---- onset: softplus + sigmoid via exp2/rcp/log2 HW ops ----
            float x  = xo[j], t = to[j];
            float e  = __builtin_amdgcn_exp2f(fabsf(x) * -LOG2E);
            float r  = __builtin_amdgcn_rcpf(1.0f + e);
            float sp = fmaf(-LN2, __builtin_amdgcn_logf(r), fmaxf(x, 0.f)); // softplus(x)
            on_sp  += sp;
            on_tsp += t * sp;
            on_pos += t * fminf(sp - x, 5.0f);
            on_cnt += t;
            float pr = (x >= 0.f) ? r : e * r;
            on_psum += pr;
            // ---- offset ----
            float y  = xf[j], u = tf[j];
            float e2 = __builtin_amdgcn_exp2f(fabsf(y) * -LOG2E);
            float r2 = __builtin_amdgcn_rcpf(1.0f + e2);
            float sp2 = fmaf(-LN2, __builtin_amdgcn_logf(r2), fmaxf(y, 0.f));
            off_sp  += sp2;
            off_tsp += u * sp2;
            off_pos += u * fminf(sp2 - y, 5.0f);
            off_cnt += u;
            float qr = (y >= 0.f) ? r2 : e2 * r2;
            off_psum += qr;
            // ---- halo stash (compile-time branch) ----
            if (i < 3) { on_h[tid * 3 + i] = pr; off_h[tid * 3 + i] = qr; }
            // ---- in-chunk violations: jg = c0+i-3, i>=3 ----
            if (i >= 3) {
                float rc = fmaxf(fmaxf(w0, w1), w2);
                cons += (rc > 0.5f && qr > 0.5f) ? rc * qr : 0.f;
            }
            w0 = w1; w1 = w2; w2 = pr;
        }
    }
    __syncthreads();

    // ---- tail violations: jg = c0+5, c0+6, c0+7 (need p8,p9,q8,q9,q10) ----
    {
        float p8, p9, q8, q9, q10;
        if (tid < BLK - 1) {
            int b = (tid + 1) * 3;
            p8 = on_h[b]; p9 = on_h[b + 1];
            q8 = off_h[b]; q9 = off_h[b + 1]; q10 = off_h[b + 2];
        } else {
            const float* onrow  = pon  + rowbase;
            const float* offrow = poff + rowbase;
            int h = C0 + COLS;
            p8  = (h     < T_LEN) ? fast_sig(onrow[h])      : 0.f;
            p9  = (h + 1 < T_LEN) ? fast_sig(onrow[h + 1])  : 0.f;
            q8  = (h     < T_LEN) ? fast_sig(offrow[h])     : 0.f;
            q9  = (h + 1 < T_LEN) ? fast_sig(offrow[h + 1]) : 0.f;
            q10 = (h + 2 < T_LEN) ? fast_sig(offrow[h + 2]) : 0.f;
        }
        // after the loop: w0=p5, w1=p6, w2=p7
        if (c0 + 5 <= T_LEN - 4) {
            float rc = fmaxf(fmaxf(w0, w1), w2);
            cons += (rc > 0.5f && q8 > 0.5f) ? rc * q8 : 0.f;
        }
        if (c0 + 6 <= T_LEN - 4) {
            float rc = fmaxf(fmaxf(w1, w2), p8);
            cons += (rc > 0.5f && q9 > 0.5f) ? rc * q9 : 0.f;
        }
        if (c0 + 7 <= T_LEN - 4) {
            float rc = fmaxf(fmaxf(w2, p8), p9);
            cons += (rc > 0.5f && q10 > 0.5f) ? rc * q10 : 0.f;
        }
    }

    // ---- block reduction: 9 partials ----
    float vals[9] = {on_pos, on_sp - on_tsp, on_cnt,
                     off_pos, off_sp - off_tsp, off_cnt,
                     on_psum, off_psum, cons};
    #pragma unroll
    for (int v = 0; v < 9; v++) {
        float a = vals[v];
        for (int o = 32; o > 0; o >>= 1) a += __shfl_down(a, o, 64);
        vals[v] = a;
    }
    const int lane = tid & 63, wid = tid >> 6;
    if (lane == 0) {
        #pragma unroll
        for (int v = 0; v < 9; v++) part[wid][v] = vals[v];
    }
    __syncthreads();
    if (tid == 0) {
        float* o = ws + (size_t)blk * 9;
        #pragma unroll
        for (int v = 0; v < 9; v++)
            o[v] = part[0][v] + part[1][v] + part[2][v] + part[3][v];
        __threadfence();                       // release: partials visible device-wide
        unsigned int old = atomicAdd(cnt, 1u); // device-scope
        is_last = (old == GRID - 1u) ? 1 : 0;
    }
    __syncthreads();
    if (!is_last) return;

    // ================= last block: final reduction =================
    __threadfence();                           // acquire
    const int r = tid;                         // one row per thread (256 rows)
    float a[9];
    #pragma unroll
    for (int v = 0; v < 9; v++) a[v] = 0.f;
    const volatile float* wv = ws;
    for (int sg = 0; sg < SEG; sg++) {
        const volatile float* p = wv + ((size_t)r * SEG + sg) * 9;
        #pragma unroll
        for (int v = 0; v < 9; v++) a[v] += p[v];
    }
    float red[9];
    red[0] = a[0]; red[1] = a[1]; red[2] = a[2];
    red[3] = a[3]; red[4] = a[4]; red[5] = a[5];
    red[6] = a[6];
    red[7] = a[8];
    red[8] = fabsf(a[6] - a[7]);               // per-row |sum_on - sum_off|
    #pragma unroll
    for (int v = 0; v < 9; v++) {
        float x = red[v];
        for (int o = 32; o > 0; o >>= 1) x += __shfl_down(x, o, 64);
        red[v] = x;
    }
    __shared__ float fin[4][9];
    if (lane == 0) {
        #pragma unroll
        for (int v = 0; v < 9; v++) fin[wid][v] = red[v];
    }
    __syncthreads();
    if (tid == 0) {
        float t[9];
        #pragma unroll
        for (int v = 0; v < 9; v++)
            t[v] = fin[0][v] + fin[1][v] + fin[2][v] + fin[3][v];
        const float N = (float)B_ROWS * (float)T_LEN;
        float pc = t[2], nc = N - pc;
        float pl = (pc > 0.f) ? t[0] / fmaxf(pc, 1.f) : 0.f;
        float nl = (nc > 0.f) ? t[1] / fmaxf(nc, 1.f) : 0.f;
        float onset_loss = 1.5f * pl + nl;
        float pc2 = t[5], nc2 = N - pc2;
        float pl2 = (pc2 > 0.f) ? t[3] / fmaxf(pc2, 1.f) : 0.f;
        float nl2 = (nc2 > 0.f) ? t[4] / fmaxf(nc2, 1.f) : 0.f;
        float offset_loss = 1.5f * pl2 + nl2;
        float cons_loss = t[7] / ((float)B_ROWS * (float)(T_LEN - 3));
        float pair_loss = t[8] / (float)B_ROWS;
        float mean_on   = t[6] / N;
        float sparsity  = 0.f;   // SPARSE_W == 0
        float total = 5.0f * onset_loss + 3.0f * offset_loss + 0.1f * cons_loss
                    + 0.05f * pair_loss + sparsity;
        out[0] = onset_loss;
        out[1] = offset_loss;
        out[2] = cons_loss;
        out[3] = pair_loss;
        out[4] = sparsity;
        out[5] = mean_on;
        out[6] = total;
    }
}

extern "C" void kernel_launch(void* const* d_in, const int* in_sizes, int n_in,
                              void* d_out, int out_size, void* d_ws, size_t ws_size,
                              hipStream_t stream) {
    const float* pon  = (const float*)d_in[0];
    const float* poff = (const float*)d_in[1];
    const float* ton  = (const float*)d_in[2];
    const float* toff = (const float*)d_in[3];
    float* ws = (float*)d_ws;                       // GRID*9 floats = 73.7 KB
    unsigned int* cnt = (unsigned int*)(ws + (size_t)GRID * 9);
    hipMemsetAsync(cnt, 0, sizeof(unsigned int), stream);   // deterministic counter reset
    loss_fused<<<GRID, BLK, 0, stream>>>(pon, poff, ton, toff, ws, cnt, (float*)d_out);
}

// Round 4
// 99.275 us; speedup vs baseline: 1.2764x; 1.2764x over previous
//
#include <hip/hip_runtime.h>
#include <math.h>

#define T_LEN 16384
#define B_ROWS 256
#define BLK 256
#define EPT 8                       // elements per thread
#define COLS (BLK * EPT)            // 2048 columns per block
#define SEG (T_LEN / COLS)          // 8 segments per row
#define GRID (B_ROWS * SEG)         // 2048 blocks

#define LOG2E 1.44269504088896340f
#define LN2   0.69314718055994531f

typedef float v4f __attribute__((ext_vector_type(4)));

__device__ __forceinline__ v4f nt_load4(const float* p) {
    return __builtin_nontemporal_load((const v4f*)p);
}

// fast sigmoid: 1 v_exp + 1 v_rcp
__device__ __forceinline__ float fast_sig(float x) {
    float e = __builtin_amdgcn_exp2f(fabsf(x) * -LOG2E);
    float r = __builtin_amdgcn_rcpf(1.0f + e);
    return (x >= 0.f) ? r : e * r;
}

// NOTE: no min-waves arg — R3's (256,8) meant 8 waves/SIMD -> VGPR clamp 32 -> scratch spills
// (WRITE_SIZE 64KB -> 88MB, VALUBusy 0.25%). Plain bound keeps ~60 VGPR, no spill.
__global__ __launch_bounds__(BLK) void loss_fused(
    const float* __restrict__ pon, const float* __restrict__ poff,
    const float* __restrict__ ton, const float* __restrict__ toff,
    float* __restrict__ ws, unsigned int* __restrict__ cnt,
    float* __restrict__ out)
{
    const int blk = blockIdx.x;
    const int row = blk >> 3;            // SEG = 8
    const int s   = blk & 7;
    const int tid = threadIdx.x;
    const int C0  = s * COLS;            // segment start (row-local col)
    const int c0  = C0 + tid * EPT;      // this thread's first col
    const size_t rowbase = (size_t)row * T_LEN;

    __shared__ float on_h[BLK * 3];      // each thread's first 3 onset probs
    __shared__ float off_h[BLK * 3];     // each thread's first 3 offset probs
    __shared__ float part[4][9];
    __shared__ int   is_last;

    // accumulators (arithmetic form, t/u are exactly 0.0 or 1.0)
    float on_sp = 0.f, on_tsp = 0.f, on_pos = 0.f, on_cnt = 0.f, on_psum = 0.f;
    float off_sp = 0.f, off_tsp = 0.f, off_pos = 0.f, off_cnt = 0.f, off_psum = 0.f;
    float cons = 0.f;
    float w0 = 0.f, w1 = 0.f, w2 = 0.f;  // rolling window of last 3 onset probs

    const float* pb  = pon  + rowbase + c0;
    const float* fb  = poff + rowbase + c0;
    const float* tb  = ton  + rowbase + c0;
    const float* ub  = toff + rowbase + c0;

    #pragma unroll
    for (int k = 0; k < EPT / 4; k++) {
        v4f xo = nt_load4(pb + 4 * k);
        v4f xf = nt_load4(fb + 4 * k);
        v4f to = nt_load4(tb + 4 * k);
        v4f tf = nt_load4(ub + 4 * k);
        #pragma unroll
        for (int j = 0; j < 4; j++) {
            const int i = 4 * k + j;      // compile-time
            // ---- onset: softplus + sigmoid via exp2/rcp/log2 HW ops ----
            float x  = xo[j], t = to[j];
            float e  = __builtin_amdgcn_exp2f(fabsf(x) * -LOG2E);
            float r  = __builtin_amdgcn_rcpf(1.0f + e);
            float sp = fmaf(-LN2, __builtin_amdgcn_logf(r), fmaxf(x, 0.f)); // softplus(x)
            on_sp  += sp;
            on_tsp += t * sp;
            on_pos += t * fminf(sp - x, 5.0f);
            on_cnt += t;
            float pr = (x >= 0.f) ? r : e * r;
            on_psum += pr;
            // ---- offset ----
            float y  = xf[j], u = tf[j];
            float e2 = __builtin_amdgcn_exp2f(fabsf(y) * -LOG2E);
            float r2 = __builtin_amdgcn_rcpf(1.0f + e2);
            float sp2 = fmaf(-LN2, __builtin_amdgcn_logf(r2), fmaxf(y, 0.f));
            off_sp  += sp2;
            off_tsp += u * sp2;
            off_pos += u * fminf(sp2 - y, 5.0f);
            off_cnt += u;
            float qr = (y >= 0.f) ? r2 : e2 * r2;
            off_psum += qr;
            // ---- halo stash (compile-time branch) ----
            if (i < 3) { on_h[tid * 3 + i] = pr; off_h[tid * 3 + i] = qr; }
            // ---- in-chunk violations: jg = c0+i-3, i>=3 ----
            if (i >= 3) {
                float rc = fmaxf(fmaxf(w0, w1), w2);
                cons += (rc > 0.5f && qr > 0.5f) ? rc * qr : 0.f;
            }
            w0 = w1; w1 = w2; w2 = pr;
        }
    }
    __syncthreads();

    // ---- tail violations: jg = c0+5, c0+6, c0+7 (need p8,p9,q8,q9,q10) ----
    {
        float p8, p9, q8, q9, q10;
        if (tid < BLK - 1) {
            int b = (tid + 1) * 3;
            p8 = on_h[b]; p9 = on_h[b + 1];
            q8 = off_h[b]; q9 = off_h[b + 1]; q10 = off_h[b + 2];
        } else {
            const float* onrow  = pon  + rowbase;
            const float* offrow = poff + rowbase;
            int h = C0 + COLS;
            p8  = (h     < T_LEN) ? fast_sig(onrow[h])      : 0.f;
            p9  = (h + 1 < T_LEN) ? fast_sig(onrow[h + 1])  : 0.f;
            q8  = (h     < T_LEN) ? fast_sig(offrow[h])     : 0.f;
            q9  = (h + 1 < T_LEN) ? fast_sig(offrow[h + 1]) : 0.f;
            q10 = (h + 2 < T_LEN) ? fast_sig(offrow[h + 2]) : 0.f;
        }
        // after the loop: w0=p5, w1=p6, w2=p7
        if (c0 + 5 <= T_LEN - 4) {
            float rc = fmaxf(fmaxf(w0, w1), w2);
            cons += (rc > 0.5f && q8 > 0.5f) ? rc * q8 : 0.f;
        }
        if (c0 + 6 <= T_LEN - 4) {
            float rc = fmaxf(fmaxf(w1, w2), p8);
            cons += (rc > 0.5f && q9 > 0.5f) ? rc * q9 : 0.f;
        }
        if (c0 + 7 <= T_LEN - 4) {
            float rc = fmaxf(fmaxf(w2, p8), p9);
            cons += (rc > 0.5f && q10 > 0.5f) ? rc * q10 : 0.f;
        }
    }

    // ---- block reduction: 9 partials ----
    float vals[9] = {on_pos, on_sp - on_tsp, on_cnt,
                     off_pos, off_sp - off_tsp, off_cnt,
                     on_psum, off_psum, cons};
    #pragma unroll
    for (int v = 0; v < 9; v++) {
        float a = vals[v];
        for (int o = 32; o > 0; o >>= 1) a += __shfl_down(a, o, 64);
        vals[v] = a;
    }
    const int lane = tid & 63, wid = tid >> 6;
    if (lane == 0) {
        #pragma unroll
        for (int v = 0; v < 9; v++) part[wid][v] = vals[v];
    }
    __syncthreads();
    if (tid == 0) {
        float* o = ws + (size_t)blk * 9;
        #pragma unroll
        for (int v = 0; v < 9; v++)
            o[v] = part[0][v] + part[1][v] + part[2][v] + part[3][v];
        __threadfence();                       // release: partials visible device-wide
        unsigned int old = atomicAdd(cnt, 1u); // device-scope
        is_last = (old == GRID - 1u) ? 1 : 0;
    }
    __syncthreads();
    if (!is_last) return;

    // ================= last block: final reduction =================
    __threadfence();                           // acquire
    const int r = tid;                         // one row per thread (256 rows)
    float a[9];
    #pragma unroll
    for (int v = 0; v < 9; v++) a[v] = 0.f;
    const volatile float* wv = ws;
    for (int sg = 0; sg < SEG; sg++) {
        const volatile float* p = wv + ((size_t)r * SEG + sg) * 9;
        #pragma unroll
        for (int v = 0; v < 9; v++) a[v] += p[v];
    }
    float red[9];
    red[0] = a[0]; red[1] = a[1]; red[2] = a[2];
    red[3] = a[3]; red[4] = a[4]; red[5] = a[5];
    red[6] = a[6];
    red[7] = a[8];
    red[8] = fabsf(a[6] - a[7]);               // per-row |sum_on - sum_off|
    #pragma unroll
    for (int v = 0; v < 9; v++) {
        float x = red[v];
        for (int o = 32; o > 0; o >>= 1) x += __shfl_down(x, o, 64);
        red[v] = x;
    }
    __shared__ float fin[4][9];
    if (lane == 0) {
        #pragma unroll
        for (int v = 0; v < 9; v++) fin[wid][v] = red[v];
    }
    __syncthreads();
    if (tid == 0) {
        float t[9];
        #pragma unroll
        for (int v = 0; v < 9; v++)
            t[v] = fin[0][v] + fin[1][v] + fin[2][v] + fin[3][v];
        const float N = (float)B_ROWS * (float)T_LEN;
        float pc = t[2], nc = N - pc;
        float pl = (pc > 0.f) ? t[0] / fmaxf(pc, 1.f) : 0.f;
        float nl = (nc > 0.f) ? t[1] / fmaxf(nc, 1.f) : 0.f;
        float onset_loss = 1.5f * pl + nl;
        float pc2 = t[5], nc2 = N - pc2;
        float pl2 = (pc2 > 0.f) ? t[3] / fmaxf(pc2, 1.f) : 0.f;
        float nl2 = (nc2 > 0.f) ? t[4] / fmaxf(nc2, 1.f) : 0.f;
        float offset_loss = 1.5f * pl2 + nl2;
        float cons_loss = t[7] / ((float)B_ROWS * (float)(T_LEN - 3));
        float pair_loss = t[8] / (float)B_ROWS;
        float mean_on   = t[6] / N;
        float sparsity  = 0.f;   // SPARSE_W == 0
        float total = 5.0f * onset_loss + 3.0f * offset_loss + 0.1f * cons_loss
                    + 0.05f * pair_loss + sparsity;
        out[0] = onset_loss;
        out[1] = offset_loss;
        out[2] = cons_loss;
        out[3] = pair_loss;
        out[4] = sparsity;
        out[5] = mean_on;
        out[6] = total;
    }
}

extern "C" void kernel_launch(void* const* d_in, const int* in_sizes, int n_in,
                              void* d_out, int out_size, void* d_ws, size_t ws_size,
                              hipStream_t stream) {
    const float* pon  = (const float*)d_in[0];
    const float* poff = (const float*)d_in[1];
    const float* ton  = (const float*)d_in[2];
    const float* toff = (const float*)d_in[3];
    float* ws = (float*)d_ws;                       // GRID*9 floats = 73.7 KB
    unsigned int* cnt = (unsigned int*)(ws + (size_t)GRID * 9);
    hipMemsetAsync(cnt, 0, sizeof(unsigned int), stream);   // deterministic counter reset
    loss_fused<<<GRID, BLK, 0, stream>>>(pon, poff, ton, toff, ws, cnt, (float*)d_out);
}